// Round 6
// baseline (52.031 us; speedup 1.0000x reference)
//
#include <hip/hip_runtime.h>
#include <hip/hip_bf16.h>
#include <math.h>

// out[i,j] = max( (x[i]·W[j]) / (|x_i| |W_j|), 1e-10 ) + b[j]
// B=65536, IN=OUT=256, fp32 in/out.
// Round 6: R1 topology (512 thr, 8 waves x 32 rows = 2 M-tiles/wave, grid 256,
// full W bf16 in LDS swizzled) + swapped MFMA (in-lane x_len, float4 stores)
// + depth-4 x ring prefetch pre-issued before W prologue + NT x loads.
// No epilogue LDS transpose (R4/R5 proved it buys nothing on WRITE_SIZE).

using bf16x8 = __attribute__((ext_vector_type(8))) short;   // 8 bf16 = 4 VGPRs
using f32x4  = __attribute__((ext_vector_type(4))) float;

#define W_LDS_BYTES 131072                        // 256 rows * 512 B (bf16, swizzled)
#define LDS_BYTES   (W_LDS_BYTES + 1024 + 1024)   // + winv[256] + b[256]
#define EPS 1e-10f

__device__ __forceinline__ short f2bf(float f) {
    __bf16 h = (__bf16)f;                         // RNE; pairs fuse to v_cvt_pk_bf16_f32
    return __builtin_bit_cast(short, h);
}

__device__ __forceinline__ float4 ntload4(const float* p) {
    f32x4 v = __builtin_nontemporal_load((const f32x4*)p);  // x is read-once: don't pollute L2
    return float4{v[0], v[1], v[2], v[3]};
}

__global__ __launch_bounds__(512, 2) void ffn_cosnorm_kernel(
    const float* __restrict__ x, const float* __restrict__ W,
    const float* __restrict__ b, float* __restrict__ out)
{
    extern __shared__ char smem[];
    float* winv = (float*)(smem + W_LDS_BYTES);           // [256] 1/|W_j|
    float* blds = (float*)(smem + W_LDS_BYTES + 1024);    // [256] bias

    const int t    = threadIdx.x;
    const int lane = t & 63;
    const int wave = t >> 6;                  // 0..7
    const int r16  = lane & 15;               // x row within M-tile (= D col, in-lane)
    const int kg   = lane >> 4;               // 0..3 : K-slice of 8
    const int rxor = (r16 & 7) << 4;          // W-frag read swizzle
    const size_t rowb = (size_t)blockIdx.x * 256 + (size_t)wave * 32;

    const float* xp0 = x + (rowb + r16) * 256 + kg * 8;   // M-tile 0 row
    const float* xp1 = xp0 + 16 * 256;                     // M-tile 1 row

    // ---- pre-issue 4 K-steps of x for BOTH tiles: land during the W prologue ----
    float4 ra0[4], rb0[4], ra1[4], rb1[4];
    #pragma unroll
    for (int s = 0; s < 4; ++s) {
        ra0[s] = ntload4(xp0 + s * 32);  rb0[s] = ntload4(xp0 + s * 32 + 4);
        ra1[s] = ntload4(xp1 + s * 32);  rb1[s] = ntload4(xp1 + s * 32 + 4);
    }

    // ---------------- prologue: stage W (fp32->bf16, XOR-swizzled) + w_len ----------------
    {
        const int wrow = t >> 1;              // 0..255 (W row = output col j)
        const int half = t & 1;               // which 128-col half
        const float* wr = W + (size_t)wrow * 256 + half * 128;
        const int rx = (wrow & 7) << 4;       // swizzle term
        float ss = 0.f;
        #pragma unroll
        for (int i = 0; i < 16; ++i) {        // 16 groups of 8 floats
            float4 a = *(const float4*)(wr + i * 8);
            float4 c = *(const float4*)(wr + i * 8 + 4);
            ss = fmaf(a.x, a.x, ss); ss = fmaf(a.y, a.y, ss);
            ss = fmaf(a.z, a.z, ss); ss = fmaf(a.w, a.w, ss);
            ss = fmaf(c.x, c.x, ss); ss = fmaf(c.y, c.y, ss);
            ss = fmaf(c.z, c.z, ss); ss = fmaf(c.w, c.w, ss);
            bf16x8 v;
            v[0] = f2bf(a.x); v[1] = f2bf(a.y); v[2] = f2bf(a.z); v[3] = f2bf(a.w);
            v[4] = f2bf(c.x); v[5] = f2bf(c.y); v[6] = f2bf(c.z); v[7] = f2bf(c.w);
            const int off = wrow * 512 + ((half * 256 + i * 16) ^ rx);
            *(bf16x8*)(smem + off) = v;       // ds_write_b128
        }
        ss += __shfl_xor(ss, 1);              // combine the two halves
        if (!half) winv[wrow] = 1.0f / sqrtf(ss);
        if (t < 256) blds[t] = b[t];
    }
    __syncthreads();                          // only barrier in the kernel

    // ---------------- main: 2 M-tiles per wave, all 256 cols ----------------
    f32x4 acc0[16], acc1[16];
    #pragma unroll
    for (int n = 0; n < 16; ++n) {
        acc0[n] = f32x4{0.f, 0.f, 0.f, 0.f};
        acc1[n] = f32x4{0.f, 0.f, 0.f, 0.f};
    }
    float ss0 = 0.f, ss1 = 0.f;

    #pragma unroll
    for (int k0 = 0; k0 < 8; ++k0) {          // K = 8 steps of 32
        const int slot = k0 & 3;              // static after full unroll
        float4 c0a = ra0[slot], c0b = rb0[slot];
        float4 c1a = ra1[slot], c1b = rb1[slot];
        if (k0 < 4) {                         // ring refill: 4 K-steps ahead
            const float* p0 = xp0 + (k0 + 4) * 32;
            ra0[slot] = ntload4(p0);  rb0[slot] = ntload4(p0 + 4);
            const float* p1 = xp1 + (k0 + 4) * 32;
            ra1[slot] = ntload4(p1);  rb1[slot] = ntload4(p1 + 4);
        }
        bf16x8 a0, a1;
        a0[0] = f2bf(c0a.x); a0[1] = f2bf(c0a.y); a0[2] = f2bf(c0a.z); a0[3] = f2bf(c0a.w);
        a0[4] = f2bf(c0b.x); a0[5] = f2bf(c0b.y); a0[6] = f2bf(c0b.z); a0[7] = f2bf(c0b.w);
        a1[0] = f2bf(c1a.x); a1[1] = f2bf(c1a.y); a1[2] = f2bf(c1a.z); a1[3] = f2bf(c1a.w);
        a1[4] = f2bf(c1b.x); a1[5] = f2bf(c1b.y); a1[6] = f2bf(c1b.z); a1[7] = f2bf(c1b.w);
        ss0 = fmaf(c0a.x, c0a.x, ss0); ss0 = fmaf(c0a.y, c0a.y, ss0);
        ss0 = fmaf(c0a.z, c0a.z, ss0); ss0 = fmaf(c0a.w, c0a.w, ss0);
        ss0 = fmaf(c0b.x, c0b.x, ss0); ss0 = fmaf(c0b.y, c0b.y, ss0);
        ss0 = fmaf(c0b.z, c0b.z, ss0); ss0 = fmaf(c0b.w, c0b.w, ss0);
        ss1 = fmaf(c1a.x, c1a.x, ss1); ss1 = fmaf(c1a.y, c1a.y, ss1);
        ss1 = fmaf(c1a.z, c1a.z, ss1); ss1 = fmaf(c1a.w, c1a.w, ss1);
        ss1 = fmaf(c1b.x, c1b.x, ss1); ss1 = fmaf(c1b.y, c1b.y, ss1);
        ss1 = fmaf(c1b.z, c1b.z, ss1); ss1 = fmaf(c1b.w, c1b.w, ss1);

        const int cswz = (k0 * 64 + kg * 16) ^ rxor;
        #pragma unroll
        for (int n = 0; n < 16; ++n) {
            const int addr = (n * 16 + r16) * 512 + cswz;
            bf16x8 wfr = *(const bf16x8*)(smem + addr);   // ds_read_b128 -> feeds 2 MFMAs
            acc0[n] = __builtin_amdgcn_mfma_f32_16x16x32_bf16(wfr, a0, acc0[n], 0, 0, 0);
            acc1[n] = __builtin_amdgcn_mfma_f32_16x16x32_bf16(wfr, a1, acc1[n], 0, 0, 0);
        }
    }

    // ---------------- x_len: butterfly over K-groups; in-lane result ----------------
    ss0 += __shfl_xor(ss0, 16); ss0 += __shfl_xor(ss0, 32);
    ss1 += __shfl_xor(ss1, 16); ss1 += __shfl_xor(ss1, 32);
    const float inv0 = 1.0f / sqrtf(ss0);     // 1/|x_row(r16)|
    const float inv1 = 1.0f / sqrtf(ss1);     // 1/|x_row(r16+16)|

    // ---------------- epilogue: scale, clamp, +bias, direct float4 stores ----------------
    const int jb = kg * 4;
    float* op0 = out + (rowb + r16) * 256;
    float* op1 = op0 + (size_t)16 * 256;
    #pragma unroll
    for (int n = 0; n < 16; ++n) {
        float4 wv = *(const float4*)(winv + n * 16 + jb);
        float4 bv = *(const float4*)(blds + n * 16 + jb);
        f32x4 o0, o1;
        o0[0] = fmaxf(acc0[n][0] * (inv0 * wv.x), EPS) + bv.x;
        o0[1] = fmaxf(acc0[n][1] * (inv0 * wv.y), EPS) + bv.y;
        o0[2] = fmaxf(acc0[n][2] * (inv0 * wv.z), EPS) + bv.z;
        o0[3] = fmaxf(acc0[n][3] * (inv0 * wv.w), EPS) + bv.w;
        o1[0] = fmaxf(acc1[n][0] * (inv1 * wv.x), EPS) + bv.x;
        o1[1] = fmaxf(acc1[n][1] * (inv1 * wv.y), EPS) + bv.y;
        o1[2] = fmaxf(acc1[n][2] * (inv1 * wv.z), EPS) + bv.z;
        o1[3] = fmaxf(acc1[n][3] * (inv1 * wv.w), EPS) + bv.w;
        *(f32x4*)(op0 + n * 16 + jb) = o0;    // 16 rows x 64B segments; n-pairs fill lines
        *(f32x4*)(op1 + n * 16 + jb) = o1;
    }
}

extern "C" void kernel_launch(void* const* d_in, const int* in_sizes, int n_in,
                              void* d_out, int out_size, void* d_ws, size_t ws_size,
                              hipStream_t stream) {
    const float* x = (const float*)d_in[0];
    const float* W = (const float*)d_in[1];
    const float* b = (const float*)d_in[2];
    float* out = (float*)d_out;

    hipFuncSetAttribute((const void*)ffn_cosnorm_kernel,
                        hipFuncAttributeMaxDynamicSharedMemorySize, LDS_BYTES);
    ffn_cosnorm_kernel<<<dim3(256), dim3(512), LDS_BYTES, stream>>>(x, W, b, out);
}

// Round 7
// 41.920 us; speedup vs baseline: 1.2412x; 1.2412x over previous
//
#include <hip/hip_runtime.h>
#include <hip/hip_bf16.h>
#include <math.h>

// out[i,j] = max( (x[i]·W[j]) / (|x_i| |W_j|), 1e-10 ) + b[j]
// B=65536, IN=OUT=256, fp32 in/out.
// Round 7: R6 topology, but ALL x loads issued at kernel start (16 loads/wave,
// both tiles, all K) -> HBM stream saturated from t=0; x converted to bf16
// fragments after the W prologue; K-loop is pure ds_read+MFMA (no VMEM/VALU).
// No NT anywhere (R6 proved NT forfeits L3 residency across graph replays).

using bf16x8 = __attribute__((ext_vector_type(8))) short;   // 8 bf16 = 4 VGPRs
using f32x4  = __attribute__((ext_vector_type(4))) float;

#define W_LDS_BYTES 131072                        // 256 rows * 512 B (bf16, swizzled)
#define LDS_BYTES   (W_LDS_BYTES + 1024 + 1024)   // + winv[256] + b[256]
#define EPS 1e-10f

__device__ __forceinline__ short f2bf(float f) {
    __bf16 h = (__bf16)f;                         // RNE; pairs fuse to v_cvt_pk_bf16_f32
    return __builtin_bit_cast(short, h);
}

__global__ __launch_bounds__(512, 2) void ffn_cosnorm_kernel(
    const float* __restrict__ x, const float* __restrict__ W,
    const float* __restrict__ b, float* __restrict__ out)
{
    extern __shared__ char smem[];
    float* winv = (float*)(smem + W_LDS_BYTES);           // [256] 1/|W_j|
    float* blds = (float*)(smem + W_LDS_BYTES + 1024);    // [256] bias

    const int t    = threadIdx.x;
    const int lane = t & 63;
    const int wave = t >> 6;                  // 0..7
    const int r16  = lane & 15;               // x row within M-tile (= D col, in-lane)
    const int kg   = lane >> 4;               // 0..3 : K-slice of 8
    const int rxor = (r16 & 7) << 4;          // W-frag read swizzle
    const size_t rowb = (size_t)blockIdx.x * 256 + (size_t)wave * 32;

    const float* xp0 = x + (rowb + r16) * 256 + kg * 8;   // M-tile 0 row
    const float* xp1 = xp0 + 16 * 256;                     // M-tile 1 row

    // ---- issue ALL x loads NOW: 16 per thread = entire x requested at t=0 ----
    float4 f0a[8], f0b[8], f1a[8], f1b[8];    // 128 VGPR, transient
    #pragma unroll
    for (int s = 0; s < 8; ++s) {
        f0a[s] = *(const float4*)(xp0 + s * 32);
        f0b[s] = *(const float4*)(xp0 + s * 32 + 4);
        f1a[s] = *(const float4*)(xp1 + s * 32);
        f1b[s] = *(const float4*)(xp1 + s * 32 + 4);
    }

    // ---------------- prologue: stage W (fp32->bf16, XOR-swizzled) + w_len ----------------
    // Runs while the x loads drain from HBM.
    {
        const int wrow = t >> 1;              // 0..255 (W row = output col j)
        const int half = t & 1;               // which 128-col half
        const float* wr = W + (size_t)wrow * 256 + half * 128;
        const int rx = (wrow & 7) << 4;       // swizzle term
        float ss = 0.f;
        #pragma unroll
        for (int i = 0; i < 16; ++i) {        // 16 groups of 8 floats
            float4 a = *(const float4*)(wr + i * 8);
            float4 c = *(const float4*)(wr + i * 8 + 4);
            ss = fmaf(a.x, a.x, ss); ss = fmaf(a.y, a.y, ss);
            ss = fmaf(a.z, a.z, ss); ss = fmaf(a.w, a.w, ss);
            ss = fmaf(c.x, c.x, ss); ss = fmaf(c.y, c.y, ss);
            ss = fmaf(c.z, c.z, ss); ss = fmaf(c.w, c.w, ss);
            bf16x8 v;
            v[0] = f2bf(a.x); v[1] = f2bf(a.y); v[2] = f2bf(a.z); v[3] = f2bf(a.w);
            v[4] = f2bf(c.x); v[5] = f2bf(c.y); v[6] = f2bf(c.z); v[7] = f2bf(c.w);
            const int off = wrow * 512 + ((half * 256 + i * 16) ^ rx);
            *(bf16x8*)(smem + off) = v;       // ds_write_b128
        }
        ss += __shfl_xor(ss, 1);              // combine the two halves
        if (!half) winv[wrow] = 1.0f / sqrtf(ss);
        if (t < 256) blds[t] = b[t];
    }

    // ---- convert x -> bf16 fragments + fp32 sum-of-squares (loads have landed) ----
    bf16x8 xb0[8], xb1[8];                    // 64 VGPR persistent
    float ss0 = 0.f, ss1 = 0.f;
    #pragma unroll
    for (int s = 0; s < 8; ++s) {
        float4 a = f0a[s], c = f0b[s];
        bf16x8 v;
        v[0] = f2bf(a.x); v[1] = f2bf(a.y); v[2] = f2bf(a.z); v[3] = f2bf(a.w);
        v[4] = f2bf(c.x); v[5] = f2bf(c.y); v[6] = f2bf(c.z); v[7] = f2bf(c.w);
        xb0[s] = v;
        ss0 = fmaf(a.x, a.x, ss0); ss0 = fmaf(a.y, a.y, ss0);
        ss0 = fmaf(a.z, a.z, ss0); ss0 = fmaf(a.w, a.w, ss0);
        ss0 = fmaf(c.x, c.x, ss0); ss0 = fmaf(c.y, c.y, ss0);
        ss0 = fmaf(c.z, c.z, ss0); ss0 = fmaf(c.w, c.w, ss0);
        float4 a1 = f1a[s], c1 = f1b[s];
        bf16x8 w1;
        w1[0] = f2bf(a1.x); w1[1] = f2bf(a1.y); w1[2] = f2bf(a1.z); w1[3] = f2bf(a1.w);
        w1[4] = f2bf(c1.x); w1[5] = f2bf(c1.y); w1[6] = f2bf(c1.z); w1[7] = f2bf(c1.w);
        xb1[s] = w1;
        ss1 = fmaf(a1.x, a1.x, ss1); ss1 = fmaf(a1.y, a1.y, ss1);
        ss1 = fmaf(a1.z, a1.z, ss1); ss1 = fmaf(a1.w, a1.w, ss1);
        ss1 = fmaf(c1.x, c1.x, ss1); ss1 = fmaf(c1.y, c1.y, ss1);
        ss1 = fmaf(c1.w, c1.w, ss1); ss1 = fmaf(c1.z, c1.z, ss1);
    }
    __syncthreads();                          // W staged; only barrier in the kernel

    // ---------------- K-loop: pure LDS + MFMA, zero memory dependence ----------------
    f32x4 acc0[16], acc1[16];
    #pragma unroll
    for (int n = 0; n < 16; ++n) {
        acc0[n] = f32x4{0.f, 0.f, 0.f, 0.f};
        acc1[n] = f32x4{0.f, 0.f, 0.f, 0.f};
    }
    #pragma unroll
    for (int k0 = 0; k0 < 8; ++k0) {          // K = 8 steps of 32
        const int cswz = (k0 * 64 + kg * 16) ^ rxor;
        #pragma unroll
        for (int n = 0; n < 16; ++n) {
            const int addr = (n * 16 + r16) * 512 + cswz;
            bf16x8 wfr = *(const bf16x8*)(smem + addr);   // ds_read_b128 -> 2 MFMAs
            acc0[n] = __builtin_amdgcn_mfma_f32_16x16x32_bf16(wfr, xb0[k0], acc0[n], 0, 0, 0);
            acc1[n] = __builtin_amdgcn_mfma_f32_16x16x32_bf16(wfr, xb1[k0], acc1[n], 0, 0, 0);
        }
    }

    // ---------------- x_len: butterfly over K-groups; in-lane result ----------------
    ss0 += __shfl_xor(ss0, 16); ss0 += __shfl_xor(ss0, 32);
    ss1 += __shfl_xor(ss1, 16); ss1 += __shfl_xor(ss1, 32);
    const float inv0 = 1.0f / sqrtf(ss0);     // 1/|x_row(r16)|
    const float inv1 = 1.0f / sqrtf(ss1);     // 1/|x_row(r16+16)|

    // ---------------- epilogue: scale, clamp, +bias, direct float4 stores ----------------
    const int jb = kg * 4;
    float* op0 = out + (rowb + r16) * 256;
    float* op1 = op0 + (size_t)16 * 256;
    #pragma unroll
    for (int n = 0; n < 16; ++n) {
        float4 wv = *(const float4*)(winv + n * 16 + jb);
        float4 bv = *(const float4*)(blds + n * 16 + jb);
        f32x4 o0, o1;
        o0[0] = fmaxf(acc0[n][0] * (inv0 * wv.x), EPS) + bv.x;
        o0[1] = fmaxf(acc0[n][1] * (inv0 * wv.y), EPS) + bv.y;
        o0[2] = fmaxf(acc0[n][2] * (inv0 * wv.z), EPS) + bv.z;
        o0[3] = fmaxf(acc0[n][3] * (inv0 * wv.w), EPS) + bv.w;
        o1[0] = fmaxf(acc1[n][0] * (inv1 * wv.x), EPS) + bv.x;
        o1[1] = fmaxf(acc1[n][1] * (inv1 * wv.y), EPS) + bv.y;
        o1[2] = fmaxf(acc1[n][2] * (inv1 * wv.z), EPS) + bv.z;
        o1[3] = fmaxf(acc1[n][3] * (inv1 * wv.w), EPS) + bv.w;
        *(f32x4*)(op0 + n * 16 + jb) = o0;    // adjacent n pairs complete 128B lines
        *(f32x4*)(op1 + n * 16 + jb) = o1;
    }
}

extern "C" void kernel_launch(void* const* d_in, const int* in_sizes, int n_in,
                              void* d_out, int out_size, void* d_ws, size_t ws_size,
                              hipStream_t stream) {
    const float* x = (const float*)d_in[0];
    const float* W = (const float*)d_in[1];
    const float* b = (const float*)d_in[2];
    float* out = (float*)d_out;

    hipFuncSetAttribute((const void*)ffn_cosnorm_kernel,
                        hipFuncAttributeMaxDynamicSharedMemorySize, LDS_BYTES);
    ffn_cosnorm_kernel<<<dim3(256), dim3(512), LDS_BYTES, stream>>>(x, W, b, out);
}